// Round 5
// baseline (1110.890 us; speedup 1.0000x reference)
//
#include <hip/hip_runtime.h>
#include <hip/hip_cooperative_groups.h>

namespace cg = cooperative_groups;

// ---------------------------------------------------------------------------
// TAGCN node regression: 3 TAGConv layers (K=4) + linear head, fp32 math.
// R14: zero-global-atomic CSR build (two-level bucket sort).
// R15: 4-edge quad software-pipelined gather (102->91us per ptag64).
// R16: octet-split gather for F=64 (91->86us).
// R17: NC=4 node batching in ptag64. mm_acc was re-streaming Wl from LDS per
// node: 16 lanes x 64 iter x 20B = 20.5KB/node -> ~2.05GB LDS/dispatch
// (~26us @ 78TB/s) + 512 LDS instrs/node. Batch 4 nodes per 16-lane group:
// one Wl read feeds 4 FMAs -> 512B/node (2.5x less LDS traffic, 1.6x fewer
// LDS instrs). LDS 32KiB/block (5 blocks/CU, same occupancy). Gathers for
// the 4 nodes run back-to-back = 4 independent edge streams for the memory
// pipe. ptag16/CSR/mega untouched.
// KNOWN: mega_k coop path never runs (occupancy API LDS-caps at 64KiB).
// ---------------------------------------------------------------------------

typedef unsigned long long u64;
typedef unsigned int u32;

__device__ __forceinline__ float h2f(unsigned short u) {
  _Float16 h;
  __builtin_memcpy(&h, &u, 2);
  return (float)h;
}
__device__ __forceinline__ unsigned short f2h(float f) {
  _Float16 h = (_Float16)f;  // RNE
  unsigned short u;
  __builtin_memcpy(&u, &h, 2);
  return u;
}
__device__ __forceinline__ ushort4 pack_h(float4 v) {
  ushort4 r;
  r.x = f2h(v.x); r.y = f2h(v.y); r.z = f2h(v.z); r.w = f2h(v.w);
  return r;
}
__device__ __forceinline__ float4 unpack_h(ushort4 u) {
  return make_float4(h2f(u.x), h2f(u.y), h2f(u.z), h2f(u.w));
}
// packed edge: [norm15 | src17]
__device__ __forceinline__ void dec_ep(u32 u, int& s, float& w) {
  s = (int)(u & 0x1FFFFu);
  w = h2f((unsigned short)(u >> 17));
}

// ---------------- atomic-free CSR build ----------------
// coarse bucket = dst >> 7 (128 nodes/bucket). NB <= 1024 (N <= 131072).
// item u64 = [0:8][w_f32:32][dst_low7:7][src:17]

__global__ __launch_bounds__(256) void k_hist(const int* __restrict__ dst, u32* __restrict__ H,
                                              int E, int CH, int NB,
                                              const float4* __restrict__ x4,
                                              ushort4* __restrict__ xh, int n4) {
  __shared__ u32 hc[1024];
  int tid = threadIdx.x, blk = blockIdx.x, nblk = gridDim.x;
  for (int i = tid; i < 1024; i += 256) hc[i] = 0;
  for (int i = blk * 256 + tid; i < n4; i += nblk * 256) xh[i] = pack_h(x4[i]);
  __syncthreads();
  int e0 = blk * CH, e1 = min(E, e0 + CH);
  for (int e = e0 + tid; e < e1; e += 256) atomicAdd(&hc[((u32)dst[e]) >> 7], 1u);
  __syncthreads();
  for (int c = tid; c < NB; c += 256) H[(size_t)c * nblk + blk] = hc[c];
}

__global__ void scanH_blocks(u32* __restrict__ H, u32* __restrict__ bsum, int n) {
  __shared__ u32 s[256];
  int tid = threadIdx.x;
  int i = blockIdx.x * 256 + tid;
  u32 v = (i < n) ? H[i] : 0;
  s[tid] = v;
  __syncthreads();
#pragma unroll
  for (int off = 1; off < 256; off <<= 1) {
    u32 t = (tid >= off) ? s[tid - off] : 0;
    __syncthreads();
    s[tid] += t;
    __syncthreads();
  }
  if (i < n) H[i] = s[tid] - v;
  if (tid == 255) bsum[blockIdx.x] = s[255];
}

__global__ void scanH_sums(u32* __restrict__ bsum, int nb) {
  __shared__ u32 s[1024];
  int tid = threadIdx.x;
  u32 v = (tid < nb) ? bsum[tid] : 0;
  s[tid] = v;
  __syncthreads();
#pragma unroll
  for (int off = 1; off < 1024; off <<= 1) {
    u32 t = (tid >= off) ? s[tid - off] : 0;
    __syncthreads();
    s[tid] += t;
    __syncthreads();
  }
  if (tid < nb) bsum[tid] = s[tid] - v;
}

__global__ void scanH_add(u32* __restrict__ H, const u32* __restrict__ bsum, int n) {
  int i = blockIdx.x * blockDim.x + threadIdx.x;
  if (i < n) H[i] += bsum[i >> 8];
}

__global__ __launch_bounds__(256) void k_scatter(const int* __restrict__ src,
                                                 const int* __restrict__ dst,
                                                 const float* __restrict__ w,
                                                 const u32* __restrict__ H,
                                                 u64* __restrict__ sorted, int E, int CH, int NB) {
  __shared__ u32 cur[1024];
  int tid = threadIdx.x, blk = blockIdx.x, nblk = gridDim.x;
  for (int c = tid; c < NB; c += 256) cur[c] = H[(size_t)c * nblk + blk];
  __syncthreads();
  int e0 = blk * CH, e1 = min(E, e0 + CH);
  for (int e = e0 + tid; e < e1; e += 256) {
    int d = dst[e];
    int c = ((u32)d) >> 7;
    u32 p = atomicAdd(&cur[c], 1u);
    u64 it = (u64)(u32)src[e] | ((u64)((u32)d & 127u) << 17) |
             ((u64)__float_as_uint(w[e]) << 24);
    sorted[p] = it;
  }
}

#define BCAP 6144
__global__ __launch_bounds__(256) void k_bucket(u64* __restrict__ sorted,
                                                const u32* __restrict__ H, int NBLK,
                                                int* __restrict__ ptr, float* __restrict__ dinv,
                                                int N, int E, int NB) {
  __shared__ u64 stage[BCAP];
  __shared__ u32 cnt[128], base[128], cur[128], tmp[128];
  __shared__ float ws[128];
  int c = blockIdx.x, tid = threadIdx.x;
  int b0 = (int)H[(size_t)c * NBLK];
  int b1 = (c + 1 < NB) ? (int)H[(size_t)(c + 1) * NBLK] : E;
  int m = b1 - b0;
  if (tid < 128) { cnt[tid] = 0; ws[tid] = 0.f; }
  __syncthreads();
  for (int i = tid; i < m; i += 256) {
    u64 it = sorted[b0 + i];
    stage[i] = it;
    int lo = (int)((it >> 17) & 127u);
    atomicAdd(&cnt[lo], 1u);
    atomicAdd(&ws[lo], __uint_as_float((u32)(it >> 24)));
  }
  __syncthreads();
  u32 v = (tid < 128) ? cnt[tid] : 0;
  if (tid < 128) tmp[tid] = v;
  __syncthreads();
#pragma unroll
  for (int off = 1; off < 128; off <<= 1) {
    u32 t = 0;
    if (tid < 128 && tid >= off) t = tmp[tid - off];
    __syncthreads();
    if (tid < 128) tmp[tid] += t;
    __syncthreads();
  }
  if (tid < 128) {
    base[tid] = tmp[tid] - v;
    cur[tid] = tmp[tid] - v;
    int node = c * 128 + tid;
    if (node < N) {
      ptr[node] = b0 + (int)base[tid];
      float d = ws[tid];
      dinv[node] = (d > 0.f) ? rsqrtf(fmaxf(d, 1e-30f)) : 0.f;
    }
  }
  if (c == NB - 1 && tid == 0) ptr[N] = E;
  __syncthreads();
  for (int i = tid; i < m; i += 256) {
    u64 it = stage[i];
    int lo = (int)((it >> 17) & 127u);
    u32 p = atomicAdd(&cur[lo], 1u);
    sorted[b0 + (int)p] = it;
  }
}

__global__ __launch_bounds__(256) void k_pack(const u64* __restrict__ sorted,
                                              const float* __restrict__ dinv,
                                              const u32* __restrict__ H, int NBLK,
                                              u32* __restrict__ ep, int E, int NB) {
  int c = blockIdx.x;
  int b0 = (int)H[(size_t)c * NBLK];
  int b1 = (c + 1 < NB) ? (int)H[(size_t)(c + 1) * NBLK] : E;
  for (int i = b0 + threadIdx.x; i < b1; i += 256) {
    u64 it = sorted[i];
    int s = (int)(it & 0x1FFFFu);
    int dn = c * 128 + (int)((it >> 17) & 127u);
    float wv = __uint_as_float((u32)(it >> 24));
    float nv = dinv[s] * wv * dinv[dn];
    ep[i] = ((u32)f2h(nv) << 17) | (u32)s;
  }
}

// ---- R15 gather (4-edge quads, pipelined): used by ptag16 and mega_k ----
__device__ __forceinline__ void acc_e(float4& a, u32 pe, ushort4 h) {
  float w = h2f((unsigned short)(pe >> 17));
  a.x = fmaf(w, h2f(h.x), a.x); a.y = fmaf(w, h2f(h.y), a.y);
  a.z = fmaf(w, h2f(h.z), a.z); a.w = fmaf(w, h2f(h.w), a.w);
}

template <int F4>
__device__ __forceinline__ float4 gather(const int* __restrict__ ptr, const u32* __restrict__ ep,
                                         const ushort4* __restrict__ hin, int node, int f4) {
  int e0 = ptr[node], e1 = ptr[node + 1];
  float4 a = make_float4(0.f, 0.f, 0.f, 0.f);
  int e = e0;
  while (e < e1 && (e & 3)) {
    u32 pe = ep[e];
    acc_e(a, pe, hin[(u32)(pe & 0x1FFFFu) * F4 + f4]);
    ++e;
  }
  int nq = (e1 - e) >> 2;
  if (nq > 0) {
    uint4 p = *(const uint4*)(ep + e);
    ushort4 h0 = hin[(u32)(p.x & 0x1FFFFu) * F4 + f4];
    ushort4 h1 = hin[(u32)(p.y & 0x1FFFFu) * F4 + f4];
    ushort4 h2 = hin[(u32)(p.z & 0x1FFFFu) * F4 + f4];
    ushort4 h3 = hin[(u32)(p.w & 0x1FFFFu) * F4 + f4];
    for (int q = 1; q < nq; ++q) {
      uint4 pn = *(const uint4*)(ep + e + 4 * q);
      ushort4 g0 = hin[(u32)(pn.x & 0x1FFFFu) * F4 + f4];
      ushort4 g1 = hin[(u32)(pn.y & 0x1FFFFu) * F4 + f4];
      ushort4 g2 = hin[(u32)(pn.z & 0x1FFFFu) * F4 + f4];
      ushort4 g3 = hin[(u32)(pn.w & 0x1FFFFu) * F4 + f4];
      acc_e(a, p.x, h0); acc_e(a, p.y, h1);
      acc_e(a, p.z, h2); acc_e(a, p.w, h3);
      p = pn; h0 = g0; h1 = g1; h2 = g2; h3 = g3;
    }
    acc_e(a, p.x, h0); acc_e(a, p.y, h1);
    acc_e(a, p.z, h2); acc_e(a, p.w, h3);
    e += nq * 4;
  }
  while (e < e1) {
    u32 pe = ep[e];
    acc_e(a, pe, hin[(u32)(pe & 0x1FFFFu) * F4 + f4]);
    ++e;
  }
  return a;
}

// ---- R16 octet gather, F=64: 8 lanes x 8 features (16B rows) ----
__device__ __forceinline__ void acc8(float4& a0, float4& a1, u32 pe, uint4 r) {
  float w = h2f((unsigned short)(pe >> 17));
  a0.x = fmaf(w, h2f((unsigned short)(r.x & 0xFFFFu)), a0.x);
  a0.y = fmaf(w, h2f((unsigned short)(r.x >> 16)), a0.y);
  a0.z = fmaf(w, h2f((unsigned short)(r.y & 0xFFFFu)), a0.z);
  a0.w = fmaf(w, h2f((unsigned short)(r.y >> 16)), a0.w);
  a1.x = fmaf(w, h2f((unsigned short)(r.z & 0xFFFFu)), a1.x);
  a1.y = fmaf(w, h2f((unsigned short)(r.z >> 16)), a1.y);
  a1.z = fmaf(w, h2f((unsigned short)(r.w & 0xFFFFu)), a1.z);
  a1.w = fmaf(w, h2f((unsigned short)(r.w >> 16)), a1.w);
}

__device__ __forceinline__ void gather64o(const int* __restrict__ ptr, const u32* __restrict__ ep,
                                          const ushort4* __restrict__ hin, int node,
                                          int f8, int o, float4& a0, float4& a1) {
  int e0 = ptr[node], e1 = ptr[node + 1];
  const u32 foff = 2u * (u32)f8;
  int e = e0;
  while (e < e1 && (e & 3)) {
    if ((e & 1) == o) {
      u32 pe = ep[e];
      uint4 r = *(const uint4*)(hin + ((u32)(pe & 0x1FFFFu) * 16u + foff));
      acc8(a0, a1, pe, r);
    }
    ++e;
  }
  int nq = (e1 - e) >> 2;
  int q = o;
  if (q < nq) {
    uint4 p = *(const uint4*)(ep + e + 4 * q);
    uint4 r0 = *(const uint4*)(hin + ((u32)(p.x & 0x1FFFFu) * 16u + foff));
    uint4 r1 = *(const uint4*)(hin + ((u32)(p.y & 0x1FFFFu) * 16u + foff));
    for (;;) {
      uint4 r2 = *(const uint4*)(hin + ((u32)(p.z & 0x1FFFFu) * 16u + foff));
      uint4 r3 = *(const uint4*)(hin + ((u32)(p.w & 0x1FFFFu) * 16u + foff));
      acc8(a0, a1, p.x, r0);
      acc8(a0, a1, p.y, r1);
      int qn = q + 2;
      if (qn >= nq) {
        acc8(a0, a1, p.z, r2);
        acc8(a0, a1, p.w, r3);
        break;
      }
      uint4 pn = *(const uint4*)(ep + e + 4 * qn);
      r0 = *(const uint4*)(hin + ((u32)(pn.x & 0x1FFFFu) * 16u + foff));
      r1 = *(const uint4*)(hin + ((u32)(pn.y & 0x1FFFFu) * 16u + foff));
      acc8(a0, a1, p.z, r2);
      acc8(a0, a1, p.w, r3);
      p = pn; q = qn;
    }
  }
  e += nq * 4;
  while (e < e1) {
    if ((e & 1) == o) {
      u32 pe = ep[e];
      uint4 r = *(const uint4*)(hin + ((u32)(pe & 0x1FFFFu) * 16u + foff));
      acc8(a0, a1, pe, r);
    }
    ++e;
  }
}

// scalar-broadcast mm accumulate (single-tile; used by mega_k)
__device__ __forceinline__ void mm_acc(const float* __restrict__ tl, const float4* __restrict__ Wl,
                                       int ln, int j4, float4& a) {
#pragma unroll 8
  for (int i = 0; i < 64; ++i) {
    float tv = tl[ln * 64 + ((((i >> 2) ^ ln) << 2) | (i & 3))];
    float4 wv = Wl[i * 16 + j4];
    a.x = fmaf(tv, wv.x, a.x); a.y = fmaf(tv, wv.y, a.y);
    a.z = fmaf(tv, wv.z, a.z); a.w = fmaf(tv, wv.w, a.w);
  }
}

// R17: NC-tile mm — one Wl float4 read feeds NC FMAs (Wl traffic / NC)
template <int NC>
__device__ __forceinline__ void mm_acc_nc(const float* __restrict__ tl, const float4* __restrict__ Wl,
                                          int ln, int j4, float4* acc) {
#pragma unroll 8
  for (int i = 0; i < 64; ++i) {
    float4 wv = Wl[i * 16 + j4];
    int sw = ln * 64 + ((((i >> 2) ^ ln) << 2) | (i & 3));
#pragma unroll
    for (int c = 0; c < NC; ++c) {
      float tv = tl[c * 1024 + sw];
      acc[c].x = fmaf(tv, wv.x, acc[c].x); acc[c].y = fmaf(tv, wv.y, acc[c].y);
      acc[c].z = fmaf(tv, wv.z, acc[c].z); acc[c].w = fmaf(tv, wv.w, acc[c].w);
    }
  }
}

// ---------- persistent cooperative kernel: layers 2+3 + head (dead path) ----------
template <int NC>
__global__ __launch_bounds__(256) void mega_k(
    const int* __restrict__ ptr, const u32* __restrict__ ep,
    ushort4* __restrict__ hb0, ushort4* __restrict__ hb1, ushort4* __restrict__ hb2,
    const float* __restrict__ W2, const float* __restrict__ b2,
    const float* __restrict__ Wout, const float* __restrict__ bout,
    float* __restrict__ outv, int n) {
  cg::grid_group grid = cg::this_grid();
  __shared__ float4 Wl[1024];
  __shared__ float4 tl4[256];
  const float* tl = (const float*)tl4;
  const int tid = threadIdx.x, j4 = tid & 15, ln = tid >> 4;
  const int nb = (int)gridDim.x;
  float4 acc[NC];

  for (int L = 0; L < 2; ++L) {
    const float* WL = W2 + (size_t)L * 5 * 4096;
#pragma unroll
    for (int c = 0; c < NC; ++c) acc[c] = make_float4(0.f, 0.f, 0.f, 0.f);
    {
      const float4* W04 = (const float4*)WL;
      for (int i = tid; i < 1024; i += 256) Wl[i] = W04[i];
      __syncthreads();
#pragma unroll
      for (int c = 0; c < NC; ++c) {
        int node = (c * nb + (int)blockIdx.x) * 16 + ln;
        float4 own = make_float4(0.f, 0.f, 0.f, 0.f);
        if (node < n) own = unpack_h(hb2[(size_t)node * 16 + j4]);
        tl4[ln * 16 + (j4 ^ ln)] = own;
        mm_acc(tl, Wl, ln, j4, acc[c]);
      }
      __syncthreads();
    }
    for (int k = 1; k <= 4; ++k) {
      const ushort4* gsrc = (k == 1) ? hb2 : ((k == 3) ? hb1 : hb0);
      ushort4* gdst = (k == 2) ? hb1 : hb0;
      const bool last = (k == 4);
      const float4* Wk4 = (const float4*)(WL + (size_t)k * 4096);
      for (int i = tid; i < 1024; i += 256) Wl[i] = Wk4[i];
      __syncthreads();
#pragma unroll
      for (int c = 0; c < NC; ++c) {
        int node = (c * nb + (int)blockIdx.x) * 16 + ln;
        float4 t = make_float4(0.f, 0.f, 0.f, 0.f);
        if (node < n) {
          t = gather<16>(ptr, ep, gsrc, node, j4);
          if (!last) gdst[(size_t)node * 16 + j4] = pack_h(t);
        }
        tl4[ln * 16 + (j4 ^ ln)] = t;
        mm_acc(tl, Wl, ln, j4, acc[c]);
      }
      if (last) {
        const float4* bias4 = (const float4*)(b2 + (size_t)L * 64);
#pragma unroll
        for (int c = 0; c < NC; ++c) {
          int node = (c * nb + (int)blockIdx.x) * 16 + ln;
          if (node >= n) continue;
          float4 a = acc[c];
          float4 b = bias4[j4];
          a.x += b.x; a.y += b.y; a.z += b.z; a.w += b.w;
          a.x = (a.x >= 0.f) ? a.x : 0.01f * a.x;
          a.y = (a.y >= 0.f) ? a.y : 0.01f * a.y;
          a.z = (a.z >= 0.f) ? a.z : 0.01f * a.z;
          a.w = (a.w >= 0.f) ? a.w : 0.01f * a.w;
          if (L == 0) {
            hb2[(size_t)node * 16 + j4] = pack_h(a);
          } else {
            float v = a.x * Wout[4 * j4] + a.y * Wout[4 * j4 + 1] +
                      a.z * Wout[4 * j4 + 2] + a.w * Wout[4 * j4 + 3];
            v += __shfl_down(v, 8, 16);
            v += __shfl_down(v, 4, 16);
            v += __shfl_down(v, 2, 16);
            v += __shfl_down(v, 1, 16);
            if (j4 == 0) outv[node] = v + bout[0];
          }
        }
      }
      if (!(L == 1 && k == 4)) {
        __threadfence();
        grid.sync();
      }
    }
  }
}

// ---------- fused prop + matmul, F=64, NC nodes per 16-lane group ----------
template <int NC, bool FIRST, bool LAST, bool HEAD>
__launch_bounds__(256)
__global__ void ptag64nc_k(const int* __restrict__ ptr, const u32* __restrict__ ep,
                           const ushort4* __restrict__ hin, ushort4* __restrict__ hout,
                           const float4* __restrict__ Wk4, const float4* __restrict__ W04,
                           ushort4* __restrict__ acch, const float4* __restrict__ bias4,
                           const float* __restrict__ Wout, const float* __restrict__ bout,
                           float* __restrict__ outv, int n) {
  __shared__ float4 Wl[1024];
  __shared__ float4 tl4[NC * 256];
  const float* tl = (const float*)tl4;
  int tid = threadIdx.x;
  for (int i = tid; i < 1024; i += 256) Wl[i] = Wk4[i];
  const int j4 = tid & 15, ln = tid >> 4;
  const int o = j4 >> 3, f8 = j4 & 7;
  const int nbase = (blockIdx.x * 16 + ln) * NC;  // first node of this group

  // ---- gather NC nodes (octet scheme), stash tiles (wave-private) ----
#pragma unroll
  for (int c = 0; c < NC; ++c) {
    int node = nbase + c;
    float4 a0 = make_float4(0.f, 0.f, 0.f, 0.f);
    float4 a1 = make_float4(0.f, 0.f, 0.f, 0.f);
    if (node < n) gather64o(ptr, ep, hin, node, f8, o, a0, a1);
    a0.x += __shfl_xor(a0.x, 8, 16); a0.y += __shfl_xor(a0.y, 8, 16);
    a0.z += __shfl_xor(a0.z, 8, 16); a0.w += __shfl_xor(a0.w, 8, 16);
    a1.x += __shfl_xor(a1.x, 8, 16); a1.y += __shfl_xor(a1.y, 8, 16);
    a1.z += __shfl_xor(a1.z, 8, 16); a1.w += __shfl_xor(a1.w, 8, 16);
    float4 t = (o == 0) ? a0 : a1;
    int g = 2 * f8 + o;
    if (node < n && !LAST) hout[(size_t)node * 16 + g] = pack_h(t);
    tl4[c * 256 + ln * 16 + (g ^ ln)] = t;
  }
  __syncthreads();  // Wl(Wk) visible to all waves

  float4 acc[NC];
#pragma unroll
  for (int c = 0; c < NC; ++c) {
    acc[c] = make_float4(0.f, 0.f, 0.f, 0.f);
    if (!FIRST) {
      int node = nbase + c;
      if (node < n) acc[c] = unpack_h(acch[(size_t)node * 16 + j4]);
    }
  }
  mm_acc_nc<NC>(tl, Wl, ln, j4, acc);

  if (FIRST) {
    __syncthreads();  // all waves done reading Wl(Wk)
    for (int i = tid; i < 1024; i += 256) Wl[i] = W04[i];
#pragma unroll
    for (int c = 0; c < NC; ++c) {
      int node = nbase + c;
      float4 own = make_float4(0.f, 0.f, 0.f, 0.f);
      if (node < n) own = unpack_h(hin[(size_t)node * 16 + j4]);
      tl4[c * 256 + ln * 16 + (j4 ^ ln)] = own;  // wave-private
    }
    __syncthreads();  // Wl(W0) visible
    mm_acc_nc<NC>(tl, Wl, ln, j4, acc);
  }

#pragma unroll
  for (int c = 0; c < NC; ++c) {
    int node = nbase + c;
    if (node >= n) continue;
    float4 a = acc[c];
    if (LAST) {
      float4 b = bias4[j4];
      a.x += b.x; a.y += b.y; a.z += b.z; a.w += b.w;
      a.x = (a.x >= 0.f) ? a.x : 0.01f * a.x;
      a.y = (a.y >= 0.f) ? a.y : 0.01f * a.y;
      a.z = (a.z >= 0.f) ? a.z : 0.01f * a.z;
      a.w = (a.w >= 0.f) ? a.w : 0.01f * a.w;
      if (HEAD) {
        float v = a.x * Wout[4 * j4] + a.y * Wout[4 * j4 + 1] +
                  a.z * Wout[4 * j4 + 2] + a.w * Wout[4 * j4 + 3];
        v += __shfl_down(v, 8, 16);
        v += __shfl_down(v, 4, 16);
        v += __shfl_down(v, 2, 16);
        v += __shfl_down(v, 1, 16);
        if (j4 == 0) outv[node] = v + bout[0];
      } else {
        hout[(size_t)node * 16 + j4] = pack_h(a);
      }
    } else {
      acch[(size_t)node * 16 + j4] = pack_h(a);
    }
  }
}

// ---------- fused prop + matmul, layer 1: F_in=16 (4 lanes/node) ----------
template <bool FIRST, bool LAST>
__launch_bounds__(256)
__global__ void ptag16_k(const int* __restrict__ ptr, const u32* __restrict__ ep,
                         const ushort4* __restrict__ hin, ushort4* __restrict__ hout,
                         const float4* __restrict__ Wk4, const float4* __restrict__ W04,
                         ushort4* __restrict__ acch, const float4* __restrict__ bias4,
                         ushort4* __restrict__ outbuf, int n) {
  __shared__ float4 Wl[256];
  __shared__ float4 W0l[FIRST ? 256 : 1];
  __shared__ float4 tl4[64 * 5];
  const float* tl = (const float*)tl4;
  int tid = threadIdx.x;
  Wl[tid] = Wk4[tid];
  if (FIRST) W0l[tid] = W04[tid];
  int gid = blockIdx.x * 256 + tid;
  int node = gid >> 2, q = tid & 3, ln = tid >> 2;

  float4 t = make_float4(0.f, 0.f, 0.f, 0.f);
  if (node < n) {
    t = gather<4>(ptr, ep, hin, node, q);
    if (!LAST) hout[(size_t)node * 4 + q] = pack_h(t);
  }
  tl4[ln * 5 + q] = t;
  __syncthreads();

  float4 a[4];
#pragma unroll
  for (int c = 0; c < 4; ++c) a[c] = make_float4(0.f, 0.f, 0.f, 0.f);
  if (!FIRST && node < n) {
#pragma unroll
    for (int c = 0; c < 4; ++c) a[c] = unpack_h(acch[(size_t)node * 16 + 4 * q + c]);
  }
#pragma unroll 4
  for (int i = 0; i < 16; ++i) {
    float tv = tl[ln * 20 + i];
#pragma unroll
    for (int c = 0; c < 4; ++c) {
      float4 wv = Wl[i * 16 + 4 * q + c];
      a[c].x = fmaf(tv, wv.x, a[c].x); a[c].y = fmaf(tv, wv.y, a[c].y);
      a[c].z = fmaf(tv, wv.z, a[c].z); a[c].w = fmaf(tv, wv.w, a[c].w);
    }
  }
  if (FIRST) {
    __syncthreads();
    float4 own = make_float4(0.f, 0.f, 0.f, 0.f);
    if (node < n) own = unpack_h(hin[(size_t)node * 4 + q]);
    tl4[ln * 5 + q] = own;
    __syncthreads();
#pragma unroll 4
    for (int i = 0; i < 16; ++i) {
      float tv = tl[ln * 20 + i];
#pragma unroll
      for (int c = 0; c < 4; ++c) {
        float4 wv = W0l[i * 16 + 4 * q + c];
        a[c].x = fmaf(tv, wv.x, a[c].x); a[c].y = fmaf(tv, wv.y, a[c].y);
        a[c].z = fmaf(tv, wv.z, a[c].z); a[c].w = fmaf(tv, wv.w, a[c].w);
      }
    }
  }
  if (node >= n) return;

  if (LAST) {
#pragma unroll
    for (int c = 0; c < 4; ++c) {
      float4 b = bias4[4 * q + c];
      a[c].x += b.x; a[c].y += b.y; a[c].z += b.z; a[c].w += b.w;
      a[c].x = (a[c].x >= 0.f) ? a[c].x : 0.01f * a[c].x;
      a[c].y = (a[c].y >= 0.f) ? a[c].y : 0.01f * a[c].y;
      a[c].z = (a[c].z >= 0.f) ? a[c].z : 0.01f * a[c].z;
      a[c].w = (a[c].w >= 0.f) ? a[c].w : 0.01f * a[c].w;
      outbuf[(size_t)node * 16 + 4 * q + c] = pack_h(a[c]);
    }
  } else {
#pragma unroll
    for (int c = 0; c < 4; ++c) acch[(size_t)node * 16 + 4 * q + c] = pack_h(a[c]);
  }
}

extern "C" void kernel_launch(void* const* d_in, const int* in_sizes, int n_in,
                              void* d_out, int out_size, void* d_ws, size_t ws_size,
                              hipStream_t stream) {
  const float* x    = (const float*)d_in[0];
  const int*   ei   = (const int*)d_in[1];
  const float* ew   = (const float*)d_in[2];
  const float* W1   = (const float*)d_in[4];
  const float* b1   = (const float*)d_in[5];
  const float* W2   = (const float*)d_in[6];
  const float* b2   = (const float*)d_in[7];
  const float* Wout = (const float*)d_in[8];
  const float* bout = (const float*)d_in[9];
  float* out = (float*)d_out;

  const int N = in_sizes[0] / 16;
  const int E = in_sizes[2];
  const int* src = ei;
  const int* dst = ei + E;

  const int NBLK = 256;
  const int CH = (E + NBLK - 1) / NBLK;
  const int NB = (N + 127) >> 7;
  const int HN = NB * NBLK;

  char* ws = (char*)d_ws;
  size_t off = 0;
  auto alloc = [&](size_t bytes) {
    char* p = ws + off;
    off = (off + bytes + 255) & ~(size_t)255;
    return p;
  };
  u32*     H      = (u32*)alloc((size_t)HN * 4);
  u32*     bsum   = (u32*)alloc(4096);
  float*   dinv   = (float*)alloc((size_t)N * 4);
  int*     ptr    = (int*)alloc(((size_t)N + 1) * 4);
  u64*     sorted = (u64*)alloc((size_t)E * 8);
  u32*     ep     = (u32*)alloc((size_t)E * 4);
  ushort4* xh     = (ushort4*)alloc((size_t)N * 16 * 2);
  ushort4* hb0    = (ushort4*)alloc((size_t)N * 64 * 2);
  ushort4* hb1    = (ushort4*)alloc((size_t)N * 64 * 2);
  ushort4* hb2    = (ushort4*)alloc((size_t)N * 64 * 2);
  ushort4* acch   = (ushort4*)alloc((size_t)N * 64 * 2);

  // ---- atomic-free CSR build ----
  k_hist<<<NBLK, 256, 0, stream>>>(dst, H, E, CH, NB, (const float4*)x, xh, N * 4);
  scanH_blocks<<<HN / 256, 256, 0, stream>>>(H, bsum, HN);
  scanH_sums<<<1, 1024, 0, stream>>>(bsum, HN / 256);
  scanH_add<<<HN / 256, 256, 0, stream>>>(H, bsum, HN);
  k_scatter<<<NBLK, 256, 0, stream>>>(src, dst, ew, H, sorted, E, CH, NB);
  k_bucket<<<NB, 256, 0, stream>>>(sorted, H, NBLK, ptr, dinv, N, E, NB);
  k_pack<<<NB, 256, 0, stream>>>(sorted, dinv, H, NBLK, ep, E, NB);

  int g4 = (N * 4 + 255) / 256;    // layer-1 fused (4 lanes/node)
  constexpr int NCP = 4;           // nodes per 16-lane group in ptag64nc
  int g64 = (N + 16 * NCP - 1) / (16 * NCP);

  auto W1k = [&](int k) { return (const float4*)(W1 + (size_t)k * 1024); };
  auto W2k = [&](int l, int k) { return (const float4*)(W2 + ((size_t)l * 5 + k) * 4096); };

  // ---- Layer 1 (16 -> 64): acc in acch, t ping-pong hb0/hb1, h1 -> hb2 ----
  ptag16_k<true,  false><<<g4, 256, 0, stream>>>(ptr, ep, xh,  hb0, W1k(1), W1k(0), acch, nullptr, nullptr, N);
  ptag16_k<false, false><<<g4, 256, 0, stream>>>(ptr, ep, hb0, hb1, W1k(2), nullptr, acch, nullptr, nullptr, N);
  ptag16_k<false, false><<<g4, 256, 0, stream>>>(ptr, ep, hb1, hb0, W1k(3), nullptr, acch, nullptr, nullptr, N);
  ptag16_k<false, true ><<<g4, 256, 0, stream>>>(ptr, ep, hb0, nullptr, W1k(4), nullptr, acch,
                                                 (const float4*)b1, hb2, N);

  // ---- Layers 2+3 + head: NC=4 batched fused kernels ----
  ptag64nc_k<NCP, true,  false, false><<<g64, 256, 0, stream>>>(ptr, ep, hb2, hb0, W2k(0,1), W2k(0,0), acch,
                                                                nullptr, nullptr, nullptr, nullptr, N);
  ptag64nc_k<NCP, false, false, false><<<g64, 256, 0, stream>>>(ptr, ep, hb0, hb1, W2k(0,2), nullptr, acch,
                                                                nullptr, nullptr, nullptr, nullptr, N);
  ptag64nc_k<NCP, false, false, false><<<g64, 256, 0, stream>>>(ptr, ep, hb1, hb0, W2k(0,3), nullptr, acch,
                                                                nullptr, nullptr, nullptr, nullptr, N);
  ptag64nc_k<NCP, false, true,  false><<<g64, 256, 0, stream>>>(ptr, ep, hb0, hb2, W2k(0,4), nullptr, acch,
                                                                (const float4*)b2, nullptr, nullptr, nullptr, N);
  ptag64nc_k<NCP, true,  false, false><<<g64, 256, 0, stream>>>(ptr, ep, hb2, hb0, W2k(1,1), W2k(1,0), acch,
                                                                nullptr, nullptr, nullptr, nullptr, N);
  ptag64nc_k<NCP, false, false, false><<<g64, 256, 0, stream>>>(ptr, ep, hb0, hb1, W2k(1,2), nullptr, acch,
                                                                nullptr, nullptr, nullptr, nullptr, N);
  ptag64nc_k<NCP, false, false, false><<<g64, 256, 0, stream>>>(ptr, ep, hb1, hb0, W2k(1,3), nullptr, acch,
                                                                nullptr, nullptr, nullptr, nullptr, N);
  ptag64nc_k<NCP, false, true,  true ><<<g64, 256, 0, stream>>>(ptr, ep, hb0, nullptr, W2k(1,4), nullptr, acch,
                                                                (const float4*)(b2 + 64), Wout, bout, out, N);
}

// Round 6
// 973.651 us; speedup vs baseline: 1.1410x; 1.1410x over previous
//
#include <hip/hip_runtime.h>

// ---------------------------------------------------------------------------
// TAGCN node regression: 3 TAGConv layers (K=4) + linear head, fp32 math.
// R14: zero-global-atomic CSR build (two-level bucket sort).
// R15: 4-edge quad software-pipelined gather (102->91us per ptag64).
// R16: octet-split gather for F=64 (91->86us).
// R17 REGRESSED (reverted): NC=4 batching grew LDS to 32KiB -> occupancy
// 64%->32%, dur 86->103us. LESSON: 20KiB LDS is the sweet spot; the kernel
// lives on TLP for gather latency. Do not grow LDS.
// R18: degree-sorted node permutation. Within a wave, node-groups have
// independent Poisson(32) degrees but run in lockstep -> wave executes
// max(deg) iters (~18% waste for 4 groups, ~25% for 16). Build perm via the
// proven atomic-free hist->scan->scatter (256 degree bins); layer kernels
// process nodes in perm order (data stays keyed by true node id -> identical
// math, rows stay coalesced). mega_k dead path deleted.
// ---------------------------------------------------------------------------

typedef unsigned long long u64;
typedef unsigned int u32;

__device__ __forceinline__ float h2f(unsigned short u) {
  _Float16 h;
  __builtin_memcpy(&h, &u, 2);
  return (float)h;
}
__device__ __forceinline__ unsigned short f2h(float f) {
  _Float16 h = (_Float16)f;  // RNE
  unsigned short u;
  __builtin_memcpy(&u, &h, 2);
  return u;
}
__device__ __forceinline__ ushort4 pack_h(float4 v) {
  ushort4 r;
  r.x = f2h(v.x); r.y = f2h(v.y); r.z = f2h(v.z); r.w = f2h(v.w);
  return r;
}
__device__ __forceinline__ float4 unpack_h(ushort4 u) {
  return make_float4(h2f(u.x), h2f(u.y), h2f(u.z), h2f(u.w));
}
// packed edge: [norm15 | src17]
__device__ __forceinline__ void dec_ep(u32 u, int& s, float& w) {
  s = (int)(u & 0x1FFFFu);
  w = h2f((unsigned short)(u >> 17));
}

// ---------------- atomic-free CSR build ----------------
// coarse bucket = dst >> 7 (128 nodes/bucket). NB <= 1024 (N <= 131072).
// item u64 = [0:8][w_f32:32][dst_low7:7][src:17]

__global__ __launch_bounds__(256) void k_hist(const int* __restrict__ dst, u32* __restrict__ H,
                                              int E, int CH, int NB,
                                              const float4* __restrict__ x4,
                                              ushort4* __restrict__ xh, int n4) {
  __shared__ u32 hc[1024];
  int tid = threadIdx.x, blk = blockIdx.x, nblk = gridDim.x;
  for (int i = tid; i < 1024; i += 256) hc[i] = 0;
  for (int i = blk * 256 + tid; i < n4; i += nblk * 256) xh[i] = pack_h(x4[i]);
  __syncthreads();
  int e0 = blk * CH, e1 = min(E, e0 + CH);
  for (int e = e0 + tid; e < e1; e += 256) atomicAdd(&hc[((u32)dst[e]) >> 7], 1u);
  __syncthreads();
  for (int c = tid; c < NB; c += 256) H[(size_t)c * nblk + blk] = hc[c];
}

__global__ void scanH_blocks(u32* __restrict__ H, u32* __restrict__ bsum, int n) {
  __shared__ u32 s[256];
  int tid = threadIdx.x;
  int i = blockIdx.x * 256 + tid;
  u32 v = (i < n) ? H[i] : 0;
  s[tid] = v;
  __syncthreads();
#pragma unroll
  for (int off = 1; off < 256; off <<= 1) {
    u32 t = (tid >= off) ? s[tid - off] : 0;
    __syncthreads();
    s[tid] += t;
    __syncthreads();
  }
  if (i < n) H[i] = s[tid] - v;
  if (tid == 255) bsum[blockIdx.x] = s[255];
}

__global__ void scanH_sums(u32* __restrict__ bsum, int nb) {
  __shared__ u32 s[1024];
  int tid = threadIdx.x;
  u32 v = (tid < nb) ? bsum[tid] : 0;
  s[tid] = v;
  __syncthreads();
#pragma unroll
  for (int off = 1; off < 1024; off <<= 1) {
    u32 t = (tid >= off) ? s[tid - off] : 0;
    __syncthreads();
    s[tid] += t;
    __syncthreads();
  }
  if (tid < nb) bsum[tid] = s[tid] - v;
}

__global__ void scanH_add(u32* __restrict__ H, const u32* __restrict__ bsum, int n) {
  int i = blockIdx.x * blockDim.x + threadIdx.x;
  if (i < n) H[i] += bsum[i >> 8];
}

__global__ __launch_bounds__(256) void k_scatter(const int* __restrict__ src,
                                                 const int* __restrict__ dst,
                                                 const float* __restrict__ w,
                                                 const u32* __restrict__ H,
                                                 u64* __restrict__ sorted, int E, int CH, int NB) {
  __shared__ u32 cur[1024];
  int tid = threadIdx.x, blk = blockIdx.x, nblk = gridDim.x;
  for (int c = tid; c < NB; c += 256) cur[c] = H[(size_t)c * nblk + blk];
  __syncthreads();
  int e0 = blk * CH, e1 = min(E, e0 + CH);
  for (int e = e0 + tid; e < e1; e += 256) {
    int d = dst[e];
    int c = ((u32)d) >> 7;
    u32 p = atomicAdd(&cur[c], 1u);
    u64 it = (u64)(u32)src[e] | ((u64)((u32)d & 127u) << 17) |
             ((u64)__float_as_uint(w[e]) << 24);
    sorted[p] = it;
  }
}

#define BCAP 6144
__global__ __launch_bounds__(256) void k_bucket(u64* __restrict__ sorted,
                                                const u32* __restrict__ H, int NBLK,
                                                int* __restrict__ ptr, float* __restrict__ dinv,
                                                int N, int E, int NB) {
  __shared__ u64 stage[BCAP];
  __shared__ u32 cnt[128], base[128], cur[128], tmp[128];
  __shared__ float ws[128];
  int c = blockIdx.x, tid = threadIdx.x;
  int b0 = (int)H[(size_t)c * NBLK];
  int b1 = (c + 1 < NB) ? (int)H[(size_t)(c + 1) * NBLK] : E;
  int m = b1 - b0;
  if (tid < 128) { cnt[tid] = 0; ws[tid] = 0.f; }
  __syncthreads();
  for (int i = tid; i < m; i += 256) {
    u64 it = sorted[b0 + i];
    stage[i] = it;
    int lo = (int)((it >> 17) & 127u);
    atomicAdd(&cnt[lo], 1u);
    atomicAdd(&ws[lo], __uint_as_float((u32)(it >> 24)));
  }
  __syncthreads();
  u32 v = (tid < 128) ? cnt[tid] : 0;
  if (tid < 128) tmp[tid] = v;
  __syncthreads();
#pragma unroll
  for (int off = 1; off < 128; off <<= 1) {
    u32 t = 0;
    if (tid < 128 && tid >= off) t = tmp[tid - off];
    __syncthreads();
    if (tid < 128) tmp[tid] += t;
    __syncthreads();
  }
  if (tid < 128) {
    base[tid] = tmp[tid] - v;
    cur[tid] = tmp[tid] - v;
    int node = c * 128 + tid;
    if (node < N) {
      ptr[node] = b0 + (int)base[tid];
      float d = ws[tid];
      dinv[node] = (d > 0.f) ? rsqrtf(fmaxf(d, 1e-30f)) : 0.f;
    }
  }
  if (c == NB - 1 && tid == 0) ptr[N] = E;
  __syncthreads();
  for (int i = tid; i < m; i += 256) {
    u64 it = stage[i];
    int lo = (int)((it >> 17) & 127u);
    u32 p = atomicAdd(&cur[lo], 1u);
    sorted[b0 + (int)p] = it;
  }
}

__global__ __launch_bounds__(256) void k_pack(const u64* __restrict__ sorted,
                                              const float* __restrict__ dinv,
                                              const u32* __restrict__ H, int NBLK,
                                              u32* __restrict__ ep, int E, int NB) {
  int c = blockIdx.x;
  int b0 = (int)H[(size_t)c * NBLK];
  int b1 = (c + 1 < NB) ? (int)H[(size_t)(c + 1) * NBLK] : E;
  for (int i = b0 + threadIdx.x; i < b1; i += 256) {
    u64 it = sorted[i];
    int s = (int)(it & 0x1FFFFu);
    int dn = c * 128 + (int)((it >> 17) & 127u);
    float wv = __uint_as_float((u32)(it >> 24));
    float nv = dinv[s] * wv * dinv[dn];
    ep[i] = ((u32)f2h(nv) << 17) | (u32)s;
  }
}

// ---------------- R18: degree-sorted node permutation (atomic-free) ----------------
// 256 degree bins (clamp 255). Same hist->scan->scatter machinery as the CSR
// build, applied to nodes. perm[pos] = node; consecutive slots ~equal degree.

__global__ __launch_bounds__(256) void k_dhist(const int* __restrict__ ptr, u32* __restrict__ DH,
                                               int N, int CHN) {
  __shared__ u32 h[256];
  int tid = threadIdx.x, blk = blockIdx.x;
  h[tid] = 0;
  __syncthreads();
  int i0 = blk * CHN, i1 = min(N, i0 + CHN);
  for (int i = i0 + tid; i < i1; i += 256) {
    int d = ptr[i + 1] - ptr[i];
    if (d > 255) d = 255;
    atomicAdd(&h[d], 1u);
  }
  __syncthreads();
  DH[(size_t)tid * 256 + blk] = h[tid];   // bin-major, like H
}

__global__ __launch_bounds__(256) void k_dscatter(const int* __restrict__ ptr,
                                                  const u32* __restrict__ DH,
                                                  int* __restrict__ perm, int N, int CHN) {
  __shared__ u32 cur[256];
  int tid = threadIdx.x, blk = blockIdx.x;
  cur[tid] = DH[(size_t)tid * 256 + blk];
  __syncthreads();
  int i0 = blk * CHN, i1 = min(N, i0 + CHN);
  for (int i = i0 + tid; i < i1; i += 256) {
    int d = ptr[i + 1] - ptr[i];
    if (d > 255) d = 255;
    u32 p = atomicAdd(&cur[d], 1u);
    perm[p] = i;
  }
}

// ---- R15 gather (4-edge quads, pipelined): used by ptag16 ----
__device__ __forceinline__ void acc_e(float4& a, u32 pe, ushort4 h) {
  float w = h2f((unsigned short)(pe >> 17));
  a.x = fmaf(w, h2f(h.x), a.x); a.y = fmaf(w, h2f(h.y), a.y);
  a.z = fmaf(w, h2f(h.z), a.z); a.w = fmaf(w, h2f(h.w), a.w);
}

template <int F4>
__device__ __forceinline__ float4 gather(const int* __restrict__ ptr, const u32* __restrict__ ep,
                                         const ushort4* __restrict__ hin, int node, int f4) {
  int e0 = ptr[node], e1 = ptr[node + 1];
  float4 a = make_float4(0.f, 0.f, 0.f, 0.f);
  int e = e0;
  while (e < e1 && (e & 3)) {
    u32 pe = ep[e];
    acc_e(a, pe, hin[(u32)(pe & 0x1FFFFu) * F4 + f4]);
    ++e;
  }
  int nq = (e1 - e) >> 2;
  if (nq > 0) {
    uint4 p = *(const uint4*)(ep + e);
    ushort4 h0 = hin[(u32)(p.x & 0x1FFFFu) * F4 + f4];
    ushort4 h1 = hin[(u32)(p.y & 0x1FFFFu) * F4 + f4];
    ushort4 h2 = hin[(u32)(p.z & 0x1FFFFu) * F4 + f4];
    ushort4 h3 = hin[(u32)(p.w & 0x1FFFFu) * F4 + f4];
    for (int q = 1; q < nq; ++q) {
      uint4 pn = *(const uint4*)(ep + e + 4 * q);
      ushort4 g0 = hin[(u32)(pn.x & 0x1FFFFu) * F4 + f4];
      ushort4 g1 = hin[(u32)(pn.y & 0x1FFFFu) * F4 + f4];
      ushort4 g2 = hin[(u32)(pn.z & 0x1FFFFu) * F4 + f4];
      ushort4 g3 = hin[(u32)(pn.w & 0x1FFFFu) * F4 + f4];
      acc_e(a, p.x, h0); acc_e(a, p.y, h1);
      acc_e(a, p.z, h2); acc_e(a, p.w, h3);
      p = pn; h0 = g0; h1 = g1; h2 = g2; h3 = g3;
    }
    acc_e(a, p.x, h0); acc_e(a, p.y, h1);
    acc_e(a, p.z, h2); acc_e(a, p.w, h3);
    e += nq * 4;
  }
  while (e < e1) {
    u32 pe = ep[e];
    acc_e(a, pe, hin[(u32)(pe & 0x1FFFFu) * F4 + f4]);
    ++e;
  }
  return a;
}

// ---- R16 octet gather, F=64: 8 lanes x 8 features (16B rows) ----
__device__ __forceinline__ void acc8(float4& a0, float4& a1, u32 pe, uint4 r) {
  float w = h2f((unsigned short)(pe >> 17));
  a0.x = fmaf(w, h2f((unsigned short)(r.x & 0xFFFFu)), a0.x);
  a0.y = fmaf(w, h2f((unsigned short)(r.x >> 16)), a0.y);
  a0.z = fmaf(w, h2f((unsigned short)(r.y & 0xFFFFu)), a0.z);
  a0.w = fmaf(w, h2f((unsigned short)(r.y >> 16)), a0.w);
  a1.x = fmaf(w, h2f((unsigned short)(r.z & 0xFFFFu)), a1.x);
  a1.y = fmaf(w, h2f((unsigned short)(r.z >> 16)), a1.y);
  a1.z = fmaf(w, h2f((unsigned short)(r.w & 0xFFFFu)), a1.z);
  a1.w = fmaf(w, h2f((unsigned short)(r.w >> 16)), a1.w);
}

__device__ __forceinline__ void gather64o(const int* __restrict__ ptr, const u32* __restrict__ ep,
                                          const ushort4* __restrict__ hin, int node,
                                          int f8, int o, float4& a0, float4& a1) {
  int e0 = ptr[node], e1 = ptr[node + 1];
  const u32 foff = 2u * (u32)f8;
  int e = e0;
  while (e < e1 && (e & 3)) {
    if ((e & 1) == o) {
      u32 pe = ep[e];
      uint4 r = *(const uint4*)(hin + ((u32)(pe & 0x1FFFFu) * 16u + foff));
      acc8(a0, a1, pe, r);
    }
    ++e;
  }
  int nq = (e1 - e) >> 2;
  int q = o;
  if (q < nq) {
    uint4 p = *(const uint4*)(ep + e + 4 * q);
    uint4 r0 = *(const uint4*)(hin + ((u32)(p.x & 0x1FFFFu) * 16u + foff));
    uint4 r1 = *(const uint4*)(hin + ((u32)(p.y & 0x1FFFFu) * 16u + foff));
    for (;;) {
      uint4 r2 = *(const uint4*)(hin + ((u32)(p.z & 0x1FFFFu) * 16u + foff));
      uint4 r3 = *(const uint4*)(hin + ((u32)(p.w & 0x1FFFFu) * 16u + foff));
      acc8(a0, a1, p.x, r0);
      acc8(a0, a1, p.y, r1);
      int qn = q + 2;
      if (qn >= nq) {
        acc8(a0, a1, p.z, r2);
        acc8(a0, a1, p.w, r3);
        break;
      }
      uint4 pn = *(const uint4*)(ep + e + 4 * qn);
      r0 = *(const uint4*)(hin + ((u32)(pn.x & 0x1FFFFu) * 16u + foff));
      r1 = *(const uint4*)(hin + ((u32)(pn.y & 0x1FFFFu) * 16u + foff));
      acc8(a0, a1, p.z, r2);
      acc8(a0, a1, p.w, r3);
      p = pn; q = qn;
    }
  }
  e += nq * 4;
  while (e < e1) {
    if ((e & 1) == o) {
      u32 pe = ep[e];
      uint4 r = *(const uint4*)(hin + ((u32)(pe & 0x1FFFFu) * 16u + foff));
      acc8(a0, a1, pe, r);
    }
    ++e;
  }
}

// scalar-broadcast mm accumulate: a += t(slot ln) @ W  (R6's 28-VGPR shape).
// t element i of slot ln lives at word ln*64 + (((i>>2)^ln)<<2 | (i&3)).
// Tile rows are WAVE-PRIVATE (ln = tid>>4): same-wave LDS RAW needs no barrier.
__device__ __forceinline__ void mm_acc(const float* __restrict__ tl, const float4* __restrict__ Wl,
                                       int ln, int j4, float4& a) {
#pragma unroll 8
  for (int i = 0; i < 64; ++i) {
    float tv = tl[ln * 64 + ((((i >> 2) ^ ln) << 2) | (i & 3))];
    float4 wv = Wl[i * 16 + j4];
    a.x = fmaf(tv, wv.x, a.x); a.y = fmaf(tv, wv.y, a.y);
    a.z = fmaf(tv, wv.z, a.z); a.w = fmaf(tv, wv.w, a.w);
  }
}

// ---------- fused prop + matmul, F=64 (R16 octet gather + R18 perm) ----------
template <bool FIRST, bool LAST, bool HEAD>
__launch_bounds__(256)
__global__ void ptag64_k(const int* __restrict__ ptr, const u32* __restrict__ ep,
                         const int* __restrict__ perm,
                         const ushort4* __restrict__ hin, ushort4* __restrict__ hout,
                         const float4* __restrict__ Wk4, const float4* __restrict__ W04,
                         ushort4* __restrict__ acch, const float4* __restrict__ bias4,
                         const float* __restrict__ Wout, const float* __restrict__ bout,
                         float* __restrict__ outv, int n) {
  __shared__ float4 Wl[1024];
  __shared__ float4 tl4[256];
  const float* tl = (const float*)tl4;
  int tid = threadIdx.x;
  for (int i = tid; i < 1024; i += 256) Wl[i] = Wk4[i];
  int j4 = tid & 15, ln = tid >> 4;
  int slot = blockIdx.x * 16 + ln;
  int node = (slot < n) ? perm[slot] : n;  // node==n => all guards false
  const int o = j4 >> 3, f8 = j4 & 7;

  float4 a0 = make_float4(0.f, 0.f, 0.f, 0.f);
  float4 a1 = make_float4(0.f, 0.f, 0.f, 0.f);
  if (node < n) gather64o(ptr, ep, hin, node, f8, o, a0, a1);
  // cross-octet combine: partner lane is j4^8 within the 16-lane group
  a0.x += __shfl_xor(a0.x, 8, 16); a0.y += __shfl_xor(a0.y, 8, 16);
  a0.z += __shfl_xor(a0.z, 8, 16); a0.w += __shfl_xor(a0.w, 8, 16);
  a1.x += __shfl_xor(a1.x, 8, 16); a1.y += __shfl_xor(a1.y, 8, 16);
  a1.z += __shfl_xor(a1.z, 8, 16); a1.w += __shfl_xor(a1.w, 8, 16);
  // lane (o,f8) owns float4-group g = 2*f8+o (features 8*f8+4*o ..+4)
  float4 t = (o == 0) ? a0 : a1;
  int g = 2 * f8 + o;
  if (node < n && !LAST) hout[(size_t)node * 16 + g] = pack_h(t);
  tl4[ln * 16 + (g ^ ln)] = t;
  __syncthreads();

  float4 a = make_float4(0.f, 0.f, 0.f, 0.f);
  if (!FIRST && node < n) a = unpack_h(acch[(size_t)node * 16 + j4]);
  mm_acc(tl, Wl, ln, j4, a);
  if (FIRST) {
    __syncthreads();
    for (int i = tid; i < 1024; i += 256) Wl[i] = W04[i];
    float4 own = make_float4(0.f, 0.f, 0.f, 0.f);
    if (node < n) own = unpack_h(hin[(size_t)node * 16 + j4]);
    tl4[ln * 16 + (j4 ^ ln)] = own;
    __syncthreads();
    mm_acc(tl, Wl, ln, j4, a);
  }
  if (node >= n) return;

  if (LAST) {
    float4 b = bias4[j4];
    a.x += b.x; a.y += b.y; a.z += b.z; a.w += b.w;
    a.x = (a.x >= 0.f) ? a.x : 0.01f * a.x;
    a.y = (a.y >= 0.f) ? a.y : 0.01f * a.y;
    a.z = (a.z >= 0.f) ? a.z : 0.01f * a.z;
    a.w = (a.w >= 0.f) ? a.w : 0.01f * a.w;
    if (HEAD) {
      float v = a.x * Wout[4 * j4] + a.y * Wout[4 * j4 + 1] +
                a.z * Wout[4 * j4 + 2] + a.w * Wout[4 * j4 + 3];
      v += __shfl_down(v, 8, 16);
      v += __shfl_down(v, 4, 16);
      v += __shfl_down(v, 2, 16);
      v += __shfl_down(v, 1, 16);
      if (j4 == 0) outv[node] = v + bout[0];
    } else {
      hout[(size_t)node * 16 + j4] = pack_h(a);
    }
  } else {
    acch[(size_t)node * 16 + j4] = pack_h(a);
  }
}

// ---------- fused prop + matmul, layer 1: F_in=16 (4 lanes/node + perm) ----------
template <bool FIRST, bool LAST>
__launch_bounds__(256)
__global__ void ptag16_k(const int* __restrict__ ptr, const u32* __restrict__ ep,
                         const int* __restrict__ perm,
                         const ushort4* __restrict__ hin, ushort4* __restrict__ hout,
                         const float4* __restrict__ Wk4, const float4* __restrict__ W04,
                         ushort4* __restrict__ acch, const float4* __restrict__ bias4,
                         ushort4* __restrict__ outbuf, int n) {
  __shared__ float4 Wl[256];
  __shared__ float4 W0l[FIRST ? 256 : 1];
  __shared__ float4 tl4[64 * 5];
  const float* tl = (const float*)tl4;
  int tid = threadIdx.x;
  Wl[tid] = Wk4[tid];
  if (FIRST) W0l[tid] = W04[tid];
  int gid = blockIdx.x * 256 + tid;
  int slot = gid >> 2, q = tid & 3, ln = tid >> 2;
  int node = (slot < n) ? perm[slot] : n;

  float4 t = make_float4(0.f, 0.f, 0.f, 0.f);
  if (node < n) {
    t = gather<4>(ptr, ep, hin, node, q);
    if (!LAST) hout[(size_t)node * 4 + q] = pack_h(t);
  }
  tl4[ln * 5 + q] = t;
  __syncthreads();

  float4 a[4];
#pragma unroll
  for (int c = 0; c < 4; ++c) a[c] = make_float4(0.f, 0.f, 0.f, 0.f);
  if (!FIRST && node < n) {
#pragma unroll
    for (int c = 0; c < 4; ++c) a[c] = unpack_h(acch[(size_t)node * 16 + 4 * q + c]);
  }
#pragma unroll 4
  for (int i = 0; i < 16; ++i) {
    float tv = tl[ln * 20 + i];
#pragma unroll
    for (int c = 0; c < 4; ++c) {
      float4 wv = Wl[i * 16 + 4 * q + c];
      a[c].x = fmaf(tv, wv.x, a[c].x); a[c].y = fmaf(tv, wv.y, a[c].y);
      a[c].z = fmaf(tv, wv.z, a[c].z); a[c].w = fmaf(tv, wv.w, a[c].w);
    }
  }
  if (FIRST) {
    __syncthreads();
    float4 own = make_float4(0.f, 0.f, 0.f, 0.f);
    if (node < n) own = unpack_h(hin[(size_t)node * 4 + q]);
    tl4[ln * 5 + q] = own;
    __syncthreads();
#pragma unroll 4
    for (int i = 0; i < 16; ++i) {
      float tv = tl[ln * 20 + i];
#pragma unroll
      for (int c = 0; c < 4; ++c) {
        float4 wv = W0l[i * 16 + 4 * q + c];
        a[c].x = fmaf(tv, wv.x, a[c].x); a[c].y = fmaf(tv, wv.y, a[c].y);
        a[c].z = fmaf(tv, wv.z, a[c].z); a[c].w = fmaf(tv, wv.w, a[c].w);
      }
    }
  }
  if (node >= n) return;

  if (LAST) {
#pragma unroll
    for (int c = 0; c < 4; ++c) {
      float4 b = bias4[4 * q + c];
      a[c].x += b.x; a[c].y += b.y; a[c].z += b.z; a[c].w += b.w;
      a[c].x = (a[c].x >= 0.f) ? a[c].x : 0.01f * a[c].x;
      a[c].y = (a[c].y >= 0.f) ? a[c].y : 0.01f * a[c].y;
      a[c].z = (a[c].z >= 0.f) ? a[c].z : 0.01f * a[c].z;
      a[c].w = (a[c].w >= 0.f) ? a[c].w : 0.01f * a[c].w;
      outbuf[(size_t)node * 16 + 4 * q + c] = pack_h(a[c]);
    }
  } else {
#pragma unroll
    for (int c = 0; c < 4; ++c) acch[(size_t)node * 16 + 4 * q + c] = pack_h(a[c]);
  }
}

extern "C" void kernel_launch(void* const* d_in, const int* in_sizes, int n_in,
                              void* d_out, int out_size, void* d_ws, size_t ws_size,
                              hipStream_t stream) {
  const float* x    = (const float*)d_in[0];
  const int*   ei   = (const int*)d_in[1];
  const float* ew   = (const float*)d_in[2];
  const float* W1   = (const float*)d_in[4];
  const float* b1   = (const float*)d_in[5];
  const float* W2   = (const float*)d_in[6];
  const float* b2   = (const float*)d_in[7];
  const float* Wout = (const float*)d_in[8];
  const float* bout = (const float*)d_in[9];
  float* out = (float*)d_out;

  const int N = in_sizes[0] / 16;
  const int E = in_sizes[2];
  const int* src = ei;
  const int* dst = ei + E;

  const int NBLK = 256;
  const int CH = (E + NBLK - 1) / NBLK;
  const int NB = (N + 127) >> 7;
  const int HN = NB * NBLK;
  const int CHN = (N + NBLK - 1) / NBLK;   // nodes per block for perm build

  char* ws = (char*)d_ws;
  size_t off = 0;
  auto alloc = [&](size_t bytes) {
    char* p = ws + off;
    off = (off + bytes + 255) & ~(size_t)255;
    return p;
  };
  u32*     H      = (u32*)alloc((size_t)HN * 4);
  u32*     bsum   = (u32*)alloc(4096);
  float*   dinv   = (float*)alloc((size_t)N * 4);
  int*     ptr    = (int*)alloc(((size_t)N + 1) * 4);
  u64*     sorted = (u64*)alloc((size_t)E * 8);
  u32*     ep     = (u32*)alloc((size_t)E * 4);
  u32*     DH     = (u32*)alloc((size_t)256 * 256 * 4);      // degree hist (bin,blk)
  int*     perm   = (int*)alloc((size_t)N * 4);              // degree-sorted node order
  ushort4* xh     = (ushort4*)alloc((size_t)N * 16 * 2);
  ushort4* hb0    = (ushort4*)alloc((size_t)N * 64 * 2);
  ushort4* hb1    = (ushort4*)alloc((size_t)N * 64 * 2);
  ushort4* hb2    = (ushort4*)alloc((size_t)N * 64 * 2);
  ushort4* acch   = (ushort4*)alloc((size_t)N * 64 * 2);

  // ---- atomic-free CSR build ----
  k_hist<<<NBLK, 256, 0, stream>>>(dst, H, E, CH, NB, (const float4*)x, xh, N * 4);
  scanH_blocks<<<HN / 256, 256, 0, stream>>>(H, bsum, HN);
  scanH_sums<<<1, 1024, 0, stream>>>(bsum, HN / 256);
  scanH_add<<<HN / 256, 256, 0, stream>>>(H, bsum, HN);
  k_scatter<<<NBLK, 256, 0, stream>>>(src, dst, ew, H, sorted, E, CH, NB);
  k_bucket<<<NB, 256, 0, stream>>>(sorted, H, NBLK, ptr, dinv, N, E, NB);
  k_pack<<<NB, 256, 0, stream>>>(sorted, dinv, H, NBLK, ep, E, NB);

  // ---- degree-sorted node permutation (atomic-free; reuses scanH kernels) ----
  k_dhist<<<256, 256, 0, stream>>>(ptr, DH, N, CHN);
  scanH_blocks<<<256, 256, 0, stream>>>(DH, bsum, 65536);
  scanH_sums<<<1, 1024, 0, stream>>>(bsum, 256);
  scanH_add<<<256, 256, 0, stream>>>(DH, bsum, 65536);
  k_dscatter<<<256, 256, 0, stream>>>(ptr, DH, perm, N, CHN);

  int g4  = (N * 4 + 255) / 256;   // layer-1 fused (4 lanes/node)
  int g16 = (N * 16 + 255) / 256;  // F=64 fused

  auto W1k = [&](int k) { return (const float4*)(W1 + (size_t)k * 1024); };
  auto W2k = [&](int l, int k) { return (const float4*)(W2 + ((size_t)l * 5 + k) * 4096); };

  // ---- Layer 1 (16 -> 64): acc in acch, t ping-pong hb0/hb1, h1 -> hb2 ----
  ptag16_k<true,  false><<<g4, 256, 0, stream>>>(ptr, ep, perm, xh,  hb0, W1k(1), W1k(0), acch, nullptr, nullptr, N);
  ptag16_k<false, false><<<g4, 256, 0, stream>>>(ptr, ep, perm, hb0, hb1, W1k(2), nullptr, acch, nullptr, nullptr, N);
  ptag16_k<false, false><<<g4, 256, 0, stream>>>(ptr, ep, perm, hb1, hb0, W1k(3), nullptr, acch, nullptr, nullptr, N);
  ptag16_k<false, true ><<<g4, 256, 0, stream>>>(ptr, ep, perm, hb0, nullptr, W1k(4), nullptr, acch,
                                                 (const float4*)b1, hb2, N);

  // ---- Layers 2+3 + head: R16 fused kernels (proven 20KiB-LDS shape) ----
  ptag64_k<true,  false, false><<<g16, 256, 0, stream>>>(ptr, ep, perm, hb2, hb0, W2k(0,1), W2k(0,0), acch,
                                                         nullptr, nullptr, nullptr, nullptr, N);
  ptag64_k<false, false, false><<<g16, 256, 0, stream>>>(ptr, ep, perm, hb0, hb1, W2k(0,2), nullptr, acch,
                                                         nullptr, nullptr, nullptr, nullptr, N);
  ptag64_k<false, false, false><<<g16, 256, 0, stream>>>(ptr, ep, perm, hb1, hb0, W2k(0,3), nullptr, acch,
                                                         nullptr, nullptr, nullptr, nullptr, N);
  ptag64_k<false, true,  false><<<g16, 256, 0, stream>>>(ptr, ep, perm, hb0, hb2, W2k(0,4), nullptr, acch,
                                                         (const float4*)b2, nullptr, nullptr, nullptr, N);
  ptag64_k<true,  false, false><<<g16, 256, 0, stream>>>(ptr, ep, perm, hb2, hb0, W2k(1,1), W2k(1,0), acch,
                                                         nullptr, nullptr, nullptr, nullptr, N);
  ptag64_k<false, false, false><<<g16, 256, 0, stream>>>(ptr, ep, perm, hb0, hb1, W2k(1,2), nullptr, acch,
                                                         nullptr, nullptr, nullptr, nullptr, N);
  ptag64_k<false, false, false><<<g16, 256, 0, stream>>>(ptr, ep, perm, hb1, hb0, W2k(1,3), nullptr, acch,
                                                         nullptr, nullptr, nullptr, nullptr, N);
  ptag64_k<false, true,  true ><<<g16, 256, 0, stream>>>(ptr, ep, perm, hb0, nullptr, W2k(1,4), nullptr, acch,
                                                         (const float4*)(b2 + 64), Wout, bout, out, N);
}